// Round 1
// baseline (75.381 us; speedup 1.0000x reference)
//
#include <hip/hip_runtime.h>
#include <math.h>

#define BB 16
#define PP 4096
#define TT 1024
#define JT 16
#define QTR 1024           // preds per block (P split in 4 quarters)
#define LIMKEY 0x41C80FFFu // key <= this  <=>  quantized d2 <= 25.0f (0x41C80000)

// Grid: 1024 blocks = 16 b x 16 target-tiles x 4 P-quarters. Block = 256 thr =
// 4 waves; wave owns 16 targets scanning its 1024-pred quarter (lane = p mod 64).
// Class-island encoding: x' = fma(cls, 128, x) -> cross-class d2 >= 4096,
// auto-rejected by the deferred radius test (d2 <= 25); no per-pair class
// compare. Packed key (d2_bits & ~0xFFF) | p gives argmin + lowest-p tie-break
// via one v_min_u32. Inner loop unrolled x2 over preds so two candidate keys
// for the same target fold into v_min3_u32 (11 VALU / 2 pairs vs 12).
// part[qtr][b*TT+t] fully written -> no ws init needed.
// No fences (R9: device-fence storm = +85 us). No LDS staging / SoA transpose /
// spatial hash: all tested neutral-or-worse (R5/R11/R12-14) - the residual is
// harness fill (40 us @ 83% HBM peak) + launch/latency floor.
__global__ __launch_bounds__(256) void match_kernel(const float* __restrict__ pred,
                                                    const float* __restrict__ gt,
                                                    unsigned* __restrict__ part) {
    const int blk   = blockIdx.x;
    const int b     = blk >> 6;           // 64 blocks per batch
    const int ttile = (blk >> 2) & 15;    // 64 targets per block
    const int qtr   = blk & 3;
    const int wave  = threadIdx.x >> 6;   // 0..3
    const int lane  = threadIdx.x & 63;
    const int tbase = ttile * 64 + wave * JT;
    const int pbase = qtr * QTR;

    const float* gb = gt + ((size_t)(b * TT + tbase)) * 3;
    float gx[JT], gy[JT];
    unsigned key[JT];
    #pragma unroll
    for (int j = 0; j < JT; ++j) {
        const float c = gb[j * 3 + 0];
        gx[j] = fmaf(c, 128.0f, gb[j * 3 + 1]);   // island offset by class
        gy[j] = gb[j * 3 + 2];
        key[j] = 0xFFFFFFFFu;
    }

    const float* pl = pred + (size_t)b * PP * 3 + (size_t)(pbase + lane) * 3;

    #pragma unroll 2
    for (int i = 0; i < QTR / 64; i += 2) {
        const float pc0 = pl[0];
        const float px0 = pl[1];
        const float py0 = pl[2];
        const float pc1 = pl[192];
        const float px1 = pl[193];
        const float py1 = pl[194];
        pl += 384;
        const float pxp0 = fmaf(pc0, 128.0f, px0);
        const float pxp1 = fmaf(pc1, 128.0f, px1);
        const unsigned po0 = (unsigned)(pbase + (i << 6) + lane);
        const unsigned po1 = po0 + 64u;
        #pragma unroll
        for (int j = 0; j < JT; ++j) {
            const float dx0 = pxp0 - gx[j];
            const float dy0 = py0 - gy[j];
            const float d20 = fmaf(dx0, dx0, dy0 * dy0);
            const unsigned k0 = (__float_as_uint(d20) & 0xFFFFF000u) | po0;
            const float dx1 = pxp1 - gx[j];
            const float dy1 = py1 - gy[j];
            const float d21 = fmaf(dx1, dx1, dy1 * dy1);
            const unsigned k1 = (__float_as_uint(d21) & 0xFFFFF000u) | po1;
            key[j] = min(key[j], min(k0, k1));   // -> v_min3_u32
        }
    }

    for (int off = 32; off; off >>= 1) {
        #pragma unroll
        for (int j = 0; j < JT; ++j) {
            const unsigned o = __shfl_down(key[j], off, 64);
            key[j] = min(key[j], o);
        }
    }

    if (lane == 0) {
        #pragma unroll
        for (int j = 0; j < JT; ++j)
            part[(size_t)qtr * (BB * TT) + b * TT + tbase + j] = key[j];
    }
}

// Fused count + F1: ONE single-block dispatch (was 16-block count + 1-block f1,
// i.e. two dispatches + a graph gap). 1024 threads = 16 waves; wave w owns
// batch w: min-combine the 4 quarter keys per target, radius-filter, bitmap
// distinct hit preds in its 512B LDS slice, popcount -> ssum[w]; thread 0 sums
// the 16 partials and writes the F1 scalar. 64K u32 reads from one CU are
// L2-resident and coalesced (~2-3 us), same ballpark as the old 16-block
// count, while removing one launch entirely.
__global__ __launch_bounds__(1024) void count_f1_kernel(const unsigned* __restrict__ part,
                                                        float* __restrict__ out) {
    __shared__ unsigned bm[BB][PP / 32];   // 16 x 128 words = 8 KB
    __shared__ int ssum[BB];
    const int tid  = threadIdx.x;
    const int wave = tid >> 6;             // 0..15 = batch
    const int lane = tid & 63;

    ((unsigned*)bm)[tid] = 0;
    ((unsigned*)bm)[tid + 1024] = 0;
    __syncthreads();

    const unsigned* pb = part + wave * TT;
    #pragma unroll
    for (int ii = 0; ii < TT / 64; ++ii) {
        const int i = ii * 64 + lane;
        const unsigned k = min(min(pb[i], pb[BB * TT + i]),
                               min(pb[2 * BB * TT + i], pb[3 * BB * TT + i]));
        if (k <= LIMKEY) {
            const unsigned p = k & 0xFFFu;
            atomicOr(&bm[wave][p >> 5], 1u << (p & 31));
        }
    }
    __syncthreads();

    int s = (int)__popc(bm[wave][lane]) + (int)__popc(bm[wave][lane + 64]);
    for (int off = 32; off; off >>= 1) s += __shfl_down(s, off, 64);
    if (lane == 0) ssum[wave] = s;
    __syncthreads();

    if (tid == 0) {
        int v = 0;
        #pragma unroll
        for (int b = 0; b < BB; ++b) v += ssum[b];
        const float tp = (float)v;
        const float eps = 1e-6f;
        const float fp = (float)(BB * PP) - tp;
        const float fn = (float)(BB * TT) - tp;
        const float precision = (tp + eps) / (tp + eps + fp + eps);
        const float recall    = (tp + eps) / (tp + fn + eps);
        const float f1 = 2.0f * precision * recall / (precision + recall);
        out[0] = 1.0f - f1;
    }
}

extern "C" void kernel_launch(void* const* d_in, const int* in_sizes, int n_in,
                              void* d_out, int out_size, void* d_ws, size_t ws_size,
                              hipStream_t stream) {
    const float* pred = (const float*)d_in[0];  // (B, P, 3): cls, x, y
    const float* gt   = (const float*)d_in[1];  // (B, T, 3)
    float* out = (float*)d_out;

    unsigned* part = (unsigned*)d_ws;           // 4 * B*T u32 = 256 KB

    match_kernel<<<BB * 16 * 4, 256, 0, stream>>>(pred, gt, part);
    count_f1_kernel<<<1, 1024, 0, stream>>>(part, out);
}

// Round 2
// 71.736 us; speedup vs baseline: 1.0508x; 1.0508x over previous
//
#include <hip/hip_runtime.h>
#include <math.h>

#define BB 16
#define PP 4096
#define TT 1024
#define JT 16
#define QTR 1024           // preds per block (P split in 4 quarters)
#define LIMKEY 0x41C80FFFu // key <= this  <=>  quantized d2 <= 25.0f (0x41C80000)

// Grid: 1024 blocks = 16 b x 16 target-tiles x 4 P-quarters. Block = 256 thr =
// 4 waves; wave owns 16 targets scanning its 1024-pred quarter (lane = p mod 64).
// Class-island encoding: x' = fma(cls, 128, x) -> cross-class d2 >= 4096,
// auto-rejected by the deferred radius test (d2 <= 25); no per-pair class
// compare. Packed key (d2_bits & ~0xFFF) | p gives argmin + lowest-p tie-break
// via one v_min_u32. Pred loop unrolled x2 so two candidate keys for the same
// target fold into one v_min3_u32 (11 VALU / 2 pairs vs 12).
// part[qtr][b*TT+t] fully written -> no ws init. Block 0 zeroes the 2-word
// ticket scratch for the count kernel (visible across the dispatch boundary).
// R1 lesson: single-block fused count = +3 us (one-CU 256KB scan); keep count
// at 16 blocks and fuse F1 via last-block ticket instead.
__global__ __launch_bounds__(256) void match_kernel(const float* __restrict__ pred,
                                                    const float* __restrict__ gt,
                                                    unsigned* __restrict__ part,
                                                    int* __restrict__ scratch) {
    const int blk   = blockIdx.x;
    if (blk == 0 && threadIdx.x == 0) { scratch[0] = 0; scratch[1] = 0; }
    const int b     = blk >> 6;           // 64 blocks per batch
    const int ttile = (blk >> 2) & 15;    // 64 targets per block
    const int qtr   = blk & 3;
    const int wave  = threadIdx.x >> 6;   // 0..3
    const int lane  = threadIdx.x & 63;
    const int tbase = ttile * 64 + wave * JT;
    const int pbase = qtr * QTR;

    const float* gb = gt + ((size_t)(b * TT + tbase)) * 3;
    float gx[JT], gy[JT];
    unsigned key[JT];
    #pragma unroll
    for (int j = 0; j < JT; ++j) {
        const float c = gb[j * 3 + 0];
        gx[j] = fmaf(c, 128.0f, gb[j * 3 + 1]);   // island offset by class
        gy[j] = gb[j * 3 + 2];
        key[j] = 0xFFFFFFFFu;
    }

    const float* pl = pred + (size_t)b * PP * 3 + (size_t)(pbase + lane) * 3;

    #pragma unroll 2
    for (int i = 0; i < QTR / 64; i += 2) {
        const float pc0 = pl[0];
        const float px0 = pl[1];
        const float py0 = pl[2];
        const float pc1 = pl[192];
        const float px1 = pl[193];
        const float py1 = pl[194];
        pl += 384;
        const float pxp0 = fmaf(pc0, 128.0f, px0);
        const float pxp1 = fmaf(pc1, 128.0f, px1);
        const unsigned po0 = (unsigned)(pbase + (i << 6) + lane);
        const unsigned po1 = po0 + 64u;
        #pragma unroll
        for (int j = 0; j < JT; ++j) {
            const float dx0 = pxp0 - gx[j];
            const float dy0 = py0 - gy[j];
            const float d20 = fmaf(dx0, dx0, dy0 * dy0);
            const unsigned k0 = (__float_as_uint(d20) & 0xFFFFF000u) | po0;
            const float dx1 = pxp1 - gx[j];
            const float dy1 = py1 - gy[j];
            const float d21 = fmaf(dx1, dx1, dy1 * dy1);
            const unsigned k1 = (__float_as_uint(d21) & 0xFFFFF000u) | po1;
            key[j] = min(key[j], min(k0, k1));   // -> v_min3_u32
        }
    }

    for (int off = 32; off; off >>= 1) {
        #pragma unroll
        for (int j = 0; j < JT; ++j) {
            const unsigned o = __shfl_down(key[j], off, 64);
            key[j] = min(key[j], o);
        }
    }

    if (lane == 0) {
        #pragma unroll
        for (int j = 0; j < JT; ++j)
            part[(size_t)qtr * (BB * TT) + b * TT + tbase + j] = key[j];
    }
}

// 16 blocks (one per batch, parallel across CUs): min-combine 4 quarters per
// target, radius-filter, bitmap distinct hit preds in 512B LDS, popcount.
// F1 fused via last-block ticket: each block adds its partial to scratch[0]
// (relaxed, agent scope), takes a ticket (acq_rel); ticket 15 sees all 15
// releases -> their partials are visible, computes F1. 16 single-lane atomics
// total — not the R9 fence storm.
__global__ __launch_bounds__(256) void count_f1_kernel(const unsigned* __restrict__ part,
                                                       int* __restrict__ scratch,
                                                       float* __restrict__ out) {
    __shared__ unsigned bm[PP / 32];   // 128 words
    if (threadIdx.x < 128) bm[threadIdx.x] = 0;
    __syncthreads();

    const int b = blockIdx.x;
    const unsigned* pb = part + b * TT;
    for (int i = threadIdx.x; i < TT; i += 256) {
        unsigned k = min(min(pb[i], pb[BB * TT + i]),
                         min(pb[2 * BB * TT + i], pb[3 * BB * TT + i]));
        if (k <= LIMKEY) {
            const unsigned p = k & 0xFFFu;
            atomicOr(&bm[p >> 5], 1u << (p & 31));
        }
    }
    __syncthreads();

    int sum = (threadIdx.x < 128) ? (int)__popc(bm[threadIdx.x]) : 0;
    for (int off = 32; off; off >>= 1) sum += __shfl_down(sum, off, 64);
    __shared__ int ss[4];
    if ((threadIdx.x & 63) == 0) ss[threadIdx.x >> 6] = sum;
    __syncthreads();

    if (threadIdx.x == 0) {
        const int s = ss[0] + ss[1] + ss[2] + ss[3];
        __hip_atomic_fetch_add(&scratch[0], s, __ATOMIC_RELAXED, __HIP_MEMORY_SCOPE_AGENT);
        const int t = __hip_atomic_fetch_add(&scratch[1], 1, __ATOMIC_ACQ_REL, __HIP_MEMORY_SCOPE_AGENT);
        if (t == BB - 1) {
            const int v = __hip_atomic_fetch_add(&scratch[0], 0, __ATOMIC_RELAXED, __HIP_MEMORY_SCOPE_AGENT);
            const float tp = (float)v;
            const float eps = 1e-6f;
            const float fp = (float)(BB * PP) - tp;
            const float fn = (float)(BB * TT) - tp;
            const float precision = (tp + eps) / (tp + eps + fp + eps);
            const float recall    = (tp + eps) / (tp + fn + eps);
            const float f1 = 2.0f * precision * recall / (precision + recall);
            out[0] = 1.0f - f1;
        }
    }
}

extern "C" void kernel_launch(void* const* d_in, const int* in_sizes, int n_in,
                              void* d_out, int out_size, void* d_ws, size_t ws_size,
                              hipStream_t stream) {
    const float* pred = (const float*)d_in[0];  // (B, P, 3): cls, x, y
    const float* gt   = (const float*)d_in[1];  // (B, T, 3)
    float* out = (float*)d_out;

    unsigned* part = (unsigned*)d_ws;                     // 4 * B*T u32 = 256 KB
    int* scratch = (int*)((char*)d_ws + 4 * BB * TT * 4); // 2 ints: total, ticket

    match_kernel<<<BB * 16 * 4, 256, 0, stream>>>(pred, gt, part, scratch);
    count_f1_kernel<<<BB, 256, 0, stream>>>(part, scratch, out);
}

// Round 3
// 70.532 us; speedup vs baseline: 1.0688x; 1.0171x over previous
//
#include <hip/hip_runtime.h>
#include <math.h>

#define BB 16
#define PP 4096
#define TT 1024
#define JT 16
#define QTR 1024           // preds per block (P split in 4 quarters)
#define LIMKEY 0x41C80FFFu // key <= this  <=>  quantized d2 <= 25.0f (0x41C80000)

// Grid: 1024 blocks = 16 b x 16 target-tiles x 4 P-quarters. Block = 256 thr =
// 4 waves; wave owns 16 targets; each LANE owns 4 consecutive preds per step
// (lane*4), so 4 records = 48 B = 3 aligned float4 loads -> 12 dwordx4 total
// per thread (was 48 scalar dwords, 12-line-divergent each). gt loads likewise
// 12 broadcast float4s (was 48 dwords). Class-island encoding:
// x' = fma(cls, 128, x) -> cross-class d2 >= 4096, auto-rejected by the
// deferred radius test (d2 <= 25); no per-pair class compare. Packed key
// (d2_bits & ~0xFFF) | p gives argmin + lowest-p tie-break via u32 min
// (lane->pred mapping is irrelevant: min is order-independent).
// part fully written -> no ws init. Block 0 zeroes the 2-word ticket scratch
// (visible across the dispatch boundary).
// R1: single-block fused count = +3.6 us (one-CU scan) - keep 16-block count.
// R2: f1-dispatch fusion = -0.25 us -> graph gaps are ~0.1-0.3 us; dispatch
// engineering exhausted. R9 (prev): device-fence storm = +85 us - no fences.
__global__ __launch_bounds__(256) void match_kernel(const float* __restrict__ pred,
                                                    const float* __restrict__ gt,
                                                    unsigned* __restrict__ part,
                                                    int* __restrict__ scratch) {
    const int blk   = blockIdx.x;
    if (blk == 0 && threadIdx.x == 0) { scratch[0] = 0; scratch[1] = 0; }
    const int b     = blk >> 6;           // 64 blocks per batch
    const int ttile = (blk >> 2) & 15;    // 64 targets per block
    const int qtr   = blk & 3;
    const int wave  = threadIdx.x >> 6;   // 0..3
    const int lane  = threadIdx.x & 63;
    const int tbase = ttile * 64 + wave * JT;
    const int pbase = qtr * QTR;

    // gt: 16 records (48 floats) = 12 broadcast float4 loads, register unpack.
    const float4* gb4 = (const float4*)(gt + ((size_t)(b * TT + tbase)) * 3);
    float4 g[12];
    #pragma unroll
    for (int j = 0; j < 12; ++j) g[j] = gb4[j];
    const float* gf = (const float*)g;    // constant-indexed -> stays in regs
    float gx[JT], gy[JT];
    unsigned key[JT];
    #pragma unroll
    for (int j = 0; j < JT; ++j) {
        gx[j] = fmaf(gf[3 * j + 0], 128.0f, gf[3 * j + 1]);  // island offset
        gy[j] = gf[3 * j + 2];
        key[j] = 0xFFFFFFFFu;
    }

    // Lane owns records r0 = pbase + i*256 + lane*4 .. +3.
    // float4 index: r0*3/4 = qtr*768 + i*192 + lane*3.
    const float4* pl4 = (const float4*)pred + (size_t)b * (PP * 3 / 4)
                        + (size_t)(qtr * 768 + lane * 3);

    #pragma unroll
    for (int i = 0; i < 4; ++i) {
        const float4 q0 = pl4[0];
        const float4 q1 = pl4[1];
        const float4 q2 = pl4[2];
        pl4 += 192;
        // q0 = c0 x0 y0 c1 | q1 = x1 y1 c2 x2 | q2 = y2 c3 x3 y3
        const float pxp0 = fmaf(q0.x, 128.0f, q0.y); const float py0 = q0.z;
        const float pxp1 = fmaf(q0.w, 128.0f, q1.x); const float py1 = q1.y;
        const float pxp2 = fmaf(q1.z, 128.0f, q1.w); const float py2 = q2.x;
        const float pxp3 = fmaf(q2.y, 128.0f, q2.z); const float py3 = q2.w;
        const unsigned po = (unsigned)(pbase + (i << 8) + (lane << 2));
        #pragma unroll
        for (int j = 0; j < JT; ++j) {
            const float dx0 = pxp0 - gx[j], dy0 = py0 - gy[j];
            const float dx1 = pxp1 - gx[j], dy1 = py1 - gy[j];
            const float dx2 = pxp2 - gx[j], dy2 = py2 - gy[j];
            const float dx3 = pxp3 - gx[j], dy3 = py3 - gy[j];
            const unsigned k0 = (__float_as_uint(fmaf(dx0, dx0, dy0 * dy0)) & 0xFFFFF000u) | po;
            const unsigned k1 = (__float_as_uint(fmaf(dx1, dx1, dy1 * dy1)) & 0xFFFFF000u) | (po + 1u);
            const unsigned k2 = (__float_as_uint(fmaf(dx2, dx2, dy2 * dy2)) & 0xFFFFF000u) | (po + 2u);
            const unsigned k3 = (__float_as_uint(fmaf(dx3, dx3, dy3 * dy3)) & 0xFFFFF000u) | (po + 3u);
            const unsigned k01 = min(k0, k1);
            const unsigned k23 = min(k2, k3);
            key[j] = min(key[j], min(k01, k23));   // tail folds to v_min3_u32
        }
    }

    for (int off = 32; off; off >>= 1) {
        #pragma unroll
        for (int j = 0; j < JT; ++j) {
            const unsigned o = __shfl_down(key[j], off, 64);
            key[j] = min(key[j], o);
        }
    }

    if (lane == 0) {
        #pragma unroll
        for (int j = 0; j < JT; ++j)
            part[(size_t)qtr * (BB * TT) + b * TT + tbase + j] = key[j];
    }
}

// 16 blocks (one per batch, parallel across CUs): min-combine 4 quarters per
// target, radius-filter, bitmap distinct hit preds in 512B LDS, popcount.
// F1 fused via last-block ticket: each block adds its partial to scratch[0]
// (relaxed, agent scope), takes a ticket (acq_rel); ticket 15 sees all 15
// releases -> their partials are visible, computes F1. 16 single-lane atomics
// total — not the R9 fence storm.
__global__ __launch_bounds__(256) void count_f1_kernel(const unsigned* __restrict__ part,
                                                       int* __restrict__ scratch,
                                                       float* __restrict__ out) {
    __shared__ unsigned bm[PP / 32];   // 128 words
    if (threadIdx.x < 128) bm[threadIdx.x] = 0;
    __syncthreads();

    const int b = blockIdx.x;
    const unsigned* pb = part + b * TT;
    for (int i = threadIdx.x; i < TT; i += 256) {
        unsigned k = min(min(pb[i], pb[BB * TT + i]),
                         min(pb[2 * BB * TT + i], pb[3 * BB * TT + i]));
        if (k <= LIMKEY) {
            const unsigned p = k & 0xFFFu;
            atomicOr(&bm[p >> 5], 1u << (p & 31));
        }
    }
    __syncthreads();

    int sum = (threadIdx.x < 128) ? (int)__popc(bm[threadIdx.x]) : 0;
    for (int off = 32; off; off >>= 1) sum += __shfl_down(sum, off, 64);
    __shared__ int ss[4];
    if ((threadIdx.x & 63) == 0) ss[threadIdx.x >> 6] = sum;
    __syncthreads();

    if (threadIdx.x == 0) {
        const int s = ss[0] + ss[1] + ss[2] + ss[3];
        __hip_atomic_fetch_add(&scratch[0], s, __ATOMIC_RELAXED, __HIP_MEMORY_SCOPE_AGENT);
        const int t = __hip_atomic_fetch_add(&scratch[1], 1, __ATOMIC_ACQ_REL, __HIP_MEMORY_SCOPE_AGENT);
        if (t == BB - 1) {
            const int v = __hip_atomic_fetch_add(&scratch[0], 0, __ATOMIC_RELAXED, __HIP_MEMORY_SCOPE_AGENT);
            const float tp = (float)v;
            const float eps = 1e-6f;
            const float fp = (float)(BB * PP) - tp;
            const float fn = (float)(BB * TT) - tp;
            const float precision = (tp + eps) / (tp + eps + fp + eps);
            const float recall    = (tp + eps) / (tp + fn + eps);
            const float f1 = 2.0f * precision * recall / (precision + recall);
            out[0] = 1.0f - f1;
        }
    }
}

extern "C" void kernel_launch(void* const* d_in, const int* in_sizes, int n_in,
                              void* d_out, int out_size, void* d_ws, size_t ws_size,
                              hipStream_t stream) {
    const float* pred = (const float*)d_in[0];  // (B, P, 3): cls, x, y
    const float* gt   = (const float*)d_in[1];  // (B, T, 3)
    float* out = (float*)d_out;

    unsigned* part = (unsigned*)d_ws;                     // 4 * B*T u32 = 256 KB
    int* scratch = (int*)((char*)d_ws + 4 * BB * TT * 4); // 2 ints: total, ticket

    match_kernel<<<BB * 16 * 4, 256, 0, stream>>>(pred, gt, part, scratch);
    count_f1_kernel<<<BB, 256, 0, stream>>>(part, scratch, out);
}